// Round 1
// baseline (2010.878 us; speedup 1.0000x reference)
//
#include <hip/hip_runtime.h>
#include <float.h>
#include <math.h>

#define NPTS 4096
#define NBATCH 4
#define BN (NBATCH * NPTS)   // 16384
#define EPSC 1e-12f

__device__ __forceinline__ bool dless(float d1, int i1, float d2, int i2) {
  return (d1 < d2) || ((d1 == d2) && (i1 < i2));
}

// ---------------------------------------------------------------------------
// Kernel 1: fused MLP — e, logits, sq, nd.  512 blocks x 256 thr, 32 pts/block
// ---------------------------------------------------------------------------
__device__ __forceinline__ void gemm32x128(const float (*A)[64], const float* W,
                                           const float* bias, float (*O)[128], int tid) {
  const int pi = (tid >> 5) << 2;   // point quad
  const int ci = (tid & 31) << 2;   // col quad
  float acc[4][4] = {};
  for (int k0 = 0; k0 < 64; k0 += 4) {
    alignas(16) float av[4][4], wv[4][4];
#pragma unroll
    for (int r = 0; r < 4; ++r) *(float4*)av[r] = *(const float4*)&A[pi + r][k0];
#pragma unroll
    for (int kk = 0; kk < 4; ++kk) *(float4*)wv[kk] = *(const float4*)&W[(k0 + kk) * 128 + ci];
#pragma unroll
    for (int kk = 0; kk < 4; ++kk)
#pragma unroll
      for (int r = 0; r < 4; ++r)
#pragma unroll
        for (int c = 0; c < 4; ++c)
          acc[r][c] = fmaf(av[r][kk], wv[kk][c], acc[r][c]);
  }
#pragma unroll
  for (int r = 0; r < 4; ++r)
#pragma unroll
    for (int c = 0; c < 4; ++c)
      O[pi + r][ci + c] = fmaxf(acc[r][c] + bias[ci + c], 0.f);
}

__global__ __launch_bounds__(256) void mlp_kernel(
    const float* __restrict__ conf, const float* __restrict__ native,
    const float* __restrict__ We1, const float* __restrict__ be1,
    const float* __restrict__ We2, const float* __restrict__ be2,
    const float* __restrict__ We3, const float* __restrict__ be3,
    const float* __restrict__ Ws1, const float* __restrict__ bs1,
    const float* __restrict__ Ws2, const float* __restrict__ bs2,
    float* __restrict__ e_out, float* __restrict__ logits_out,
    float* __restrict__ sq_ws, float* __restrict__ nd_ws) {
  __shared__ __align__(16) float Wbuf[8192];       // 32 KB (We1 / We2 / Ws1)
  __shared__ __align__(16) float confs[32][64];    // 8 KB (later reused for h2)
  __shared__ __align__(16) float hbuf[32][128];    // 16 KB (g then h1)
  __shared__ float nat[64];
  __shared__ float b1s[128], b2s[64], w3s[64], bs1s[128], ws2s[768], bs2s[6];
  __shared__ float be3s;

  const int tid = threadIdx.x;
  const int blk = blockIdx.x;       // 0..511
  const int b = blk >> 7;           // 128 blocks per batch
  const int pbase = (blk & 127) * 32;
  const float* confb = conf + ((size_t)b * NPTS + pbase) * 64;

  // stage conf tile + small tensors + Ws1
  for (int q = tid; q < 512; q += 256) {
    float4 v = *(const float4*)(confb + q * 4);
    *(float4*)&confs[q >> 4][(q & 15) << 2] = v;
  }
  if (tid < 64) nat[tid] = native[b * 64 + tid];
  if (tid < 128) b1s[tid] = be1[tid];
  if (tid < 64) b2s[tid] = be2[tid];
  if (tid < 64) w3s[tid] = We3[tid];
  if (tid < 128) bs1s[tid] = bs1[tid];
  for (int q = tid; q < 768; q += 256) ws2s[q] = Ws2[q];
  if (tid < 6) bs2s[tid] = bs2[tid];
  if (tid == 0) be3s = be3[0];
  for (int q = tid; q < 2048; q += 256)
    *(float4*)&Wbuf[q * 4] = *(const float4*)(Ws1 + q * 4);
  __syncthreads();

  // sq & nd — numpy-pairwise style: rounded products, 8 accumulators
  if (tid < 32) {
    float rs_[8], rn_[8];
#pragma unroll
    for (int u = 0; u < 8; ++u) {
      float c = confs[tid][u];
      rs_[u] = c * c;
      float d = c - nat[u];
      rn_[u] = d * d;
    }
    for (int d0 = 8; d0 < 64; d0 += 8) {
#pragma unroll
      for (int u = 0; u < 8; ++u) {
        float c = confs[tid][d0 + u];
        rs_[u] += c * c;
        float d = c - nat[d0 + u];
        rn_[u] += d * d;
      }
    }
    float s = ((rs_[0] + rs_[1]) + (rs_[2] + rs_[3])) + ((rs_[4] + rs_[5]) + (rs_[6] + rs_[7]));
    float n = ((rn_[0] + rn_[1]) + (rn_[2] + rn_[3])) + ((rn_[4] + rn_[5]) + (rn_[6] + rn_[7]));
    sq_ws[(size_t)b * NPTS + pbase + tid] = s;
    nd_ws[(size_t)b * NPTS + pbase + tid] = sqrtf(n);
  }

  // g = relu(conf @ Ws1 + bs1)
  gemm32x128(confs, Wbuf, bs1s, hbuf, tid);
  __syncthreads();

  // logits (uses hbuf + ws2s) while reloading Wbuf <- We1
  for (int q = tid; q < 2048; q += 256)
    *(float4*)&Wbuf[q * 4] = *(const float4*)(We1 + q * 4);
  if (tid < 192) {
    int p = tid / 6, s = tid % 6;
    float acc = 0.f;
#pragma unroll 8
    for (int h = 0; h < 128; ++h)
      acc = fmaf(hbuf[p][h], ws2s[h * 6 + s], acc);
    logits_out[((size_t)b * NPTS + pbase + p) * 6 + s] = acc + bs2s[s];
  }
  __syncthreads();

  // h1 = relu(conf @ We1 + be1)
  gemm32x128(confs, Wbuf, b1s, hbuf, tid);
  __syncthreads();

  for (int q = tid; q < 2048; q += 256)
    *(float4*)&Wbuf[q * 4] = *(const float4*)(We2 + q * 4);
  __syncthreads();

  // h2 = relu(h1 @ We2 + be2) -> confs (conf no longer needed)
  if (tid < 128) {
    const int pi = (tid >> 4) << 2;
    const int ci = (tid & 15) << 2;
    float acc[4][4] = {};
    for (int k0 = 0; k0 < 128; k0 += 4) {
      alignas(16) float av[4][4], wv[4][4];
#pragma unroll
      for (int r = 0; r < 4; ++r) *(float4*)av[r] = *(const float4*)&hbuf[pi + r][k0];
#pragma unroll
      for (int kk = 0; kk < 4; ++kk) *(float4*)wv[kk] = *(const float4*)&Wbuf[(k0 + kk) * 64 + ci];
#pragma unroll
      for (int kk = 0; kk < 4; ++kk)
#pragma unroll
        for (int r = 0; r < 4; ++r)
#pragma unroll
          for (int c = 0; c < 4; ++c)
            acc[r][c] = fmaf(av[r][kk], wv[kk][c], acc[r][c]);
    }
#pragma unroll
    for (int r = 0; r < 4; ++r)
#pragma unroll
      for (int c = 0; c < 4; ++c)
        confs[pi + r][ci + c] = fmaxf(acc[r][c] + b2s[ci + c], 0.f);
  }
  __syncthreads();

  // e = h2 @ We3 + be3
  if (tid < 32) {
    float acc = 0.f;
#pragma unroll
    for (int k = 0; k < 64; ++k)
      acc = fmaf(confs[tid][k], w3s[k], acc);
    e_out[(size_t)b * NPTS + pbase + tid] = acc + be3s;
  }
}

// ---------------------------------------------------------------------------
// Kernel 2: distance field — two passes, 64 rows/block, grid (64, B)
// ---------------------------------------------------------------------------
#define TOP10_INSERT(d_, j_)                                                  \
  do {                                                                        \
    if (dless((d_), (j_), ld[9], li[9])) {                                    \
      float cd = (d_); int ci = (j_); bool placed = false;                    \
      _Pragma("unroll")                                                       \
      for (int k = 9; k >= 1; --k) {                                          \
        bool up = !placed && dless(cd, ci, ld[k - 1], li[k - 1]);             \
        bool here = !placed && !up;                                           \
        float pd = ld[k - 1]; int pi_ = li[k - 1];                            \
        if (up) { ld[k] = pd; li[k] = pi_; }                                  \
        if (here) { ld[k] = cd; li[k] = ci; placed = true; }                  \
      }                                                                       \
      if (!placed) { ld[0] = cd; li[0] = ci; }                                \
    }                                                                         \
  } while (0)

__global__ __launch_bounds__(256) void dist_kernel(
    const float* __restrict__ conf, const float* __restrict__ sq_ws,
    const float* __restrict__ e_in, float* __restrict__ basin_out,
    float* __restrict__ depth_out, float* __restrict__ width_out) {
  __shared__ __align__(16) float As[64][68];
  __shared__ __align__(16) float Bs[64][68];
  __shared__ float sqa[64], sqjs[64], ejs[64], rs[64];
  __shared__ float mrgD[64][40];
  __shared__ int mrgI[64][40];

  const int tid = threadIdx.x;
  const int b = blockIdx.y;
  const int i0 = blockIdx.x * 64;
  const float* confb = conf + (size_t)b * NPTS * 64;
  const float* sqb = sq_ws + (size_t)b * NPTS;
  const float* eb = e_in + (size_t)b * NPTS;

  for (int q = tid; q < 1024; q += 256) {
    int row = q >> 4, k4 = (q & 15) << 2;
    *(float4*)&As[row][k4] = *(const float4*)(confb + (size_t)(i0 + row) * 64 + k4);
  }
  if (tid < 64) sqa[tid] = sqb[i0 + tid];

  const int tc = tid & 15, tr = tid >> 4;

  float ld[10];
  int li[10];
#pragma unroll
  for (int k = 0; k < 10; ++k) { ld[k] = FLT_MAX; li[k] = 0x7fffffff; }

  // ---- pass 1: top-10 per row ----
  for (int jt = 0; jt < 64; ++jt) {
    __syncthreads();  // previous tile fully consumed (also covers As readiness)
    const int j0 = jt * 64;
    for (int q = tid; q < 1024; q += 256) {
      int row = q >> 4, k4 = (q & 15) << 2;
      *(float4*)&Bs[row][k4] = *(const float4*)(confb + (size_t)(j0 + row) * 64 + k4);
    }
    if (tid < 64) sqjs[tid] = sqb[j0 + tid];
    __syncthreads();

    float acc[4][4] = {};
    for (int k0 = 0; k0 < 64; k0 += 4) {
      alignas(16) float av[4][4], bv[4][4];
#pragma unroll
      for (int r = 0; r < 4; ++r) *(float4*)av[r] = *(const float4*)&As[tr + 16 * r][k0];
#pragma unroll
      for (int c = 0; c < 4; ++c) *(float4*)bv[c] = *(const float4*)&Bs[tc + 16 * c][k0];
#pragma unroll
      for (int kk = 0; kk < 4; ++kk)
#pragma unroll
        for (int r = 0; r < 4; ++r)
#pragma unroll
          for (int c = 0; c < 4; ++c)
            acc[r][c] = fmaf(av[r][kk], bv[c][kk], acc[r][c]);
    }
    __syncthreads();  // everyone done reading Bs
#pragma unroll
    for (int r = 0; r < 4; ++r)
#pragma unroll
      for (int c = 0; c < 4; ++c) {
        int row = tr + 16 * r, col = tc + 16 * c;
        float d2 = sqa[row] + sqjs[col] - 2.f * acc[r][c];
        Bs[row][col] = sqrtf(fmaxf(d2, EPSC));
      }
    __syncthreads();
    {
      const int row = tid >> 2, q4 = tid & 3;
#pragma unroll
      for (int c = 0; c < 16; ++c) {
        int col = q4 * 16 + c;
        float d = Bs[row][col];
        int j = j0 + col;
        TOP10_INSERT(d, j);
      }
    }
  }
  __syncthreads();
  {
    const int row = tid >> 2, q4 = tid & 3;
#pragma unroll
    for (int k = 0; k < 10; ++k) {
      mrgD[row][q4 * 10 + k] = ld[k];
      mrgI[row][q4 * 10 + k] = li[k];
    }
  }
  __syncthreads();
  if (tid < 64) {
    const int row = tid;
    float e_i = eb[i0 + row];
    bool basin = true;
    float rr = 0.f;
    for (int k = 0; k < 10; ++k) {
      float bd = FLT_MAX;
      int bi = 0x7fffffff, bp = -1;
      for (int t = 0; t < 40; ++t) {
        float dd = mrgD[row][t];
        int ii = mrgI[row][t];
        if (dless(dd, ii, bd, bi)) { bd = dd; bi = ii; bp = t; }
      }
      mrgD[row][bp] = FLT_MAX;
      mrgI[row][bp] = 0x7fffffff;
      if (k >= 1) basin = basin && (e_i <= eb[bi]);
      rr = bd;
    }
    rs[row] = rr;
    basin_out[(size_t)b * NPTS + i0 + row] = basin ? 1.f : 0.f;
  }
  __syncthreads();

  float rsl[4];
#pragma unroll
  for (int r = 0; r < 4; ++r) rsl[r] = rs[tr + 16 * r];

  // ---- pass 2: masked reductions ----
  float mxe[4], sd[4];
  int cnt[4];
#pragma unroll
  for (int r = 0; r < 4; ++r) { mxe[r] = -FLT_MAX; sd[r] = 0.f; cnt[r] = 0; }

  for (int jt = 0; jt < 64; ++jt) {
    __syncthreads();
    const int j0 = jt * 64;
    for (int q = tid; q < 1024; q += 256) {
      int row = q >> 4, k4 = (q & 15) << 2;
      *(float4*)&Bs[row][k4] = *(const float4*)(confb + (size_t)(j0 + row) * 64 + k4);
    }
    if (tid < 64) { sqjs[tid] = sqb[j0 + tid]; ejs[tid] = eb[j0 + tid]; }
    __syncthreads();

    float acc[4][4] = {};
    for (int k0 = 0; k0 < 64; k0 += 4) {
      alignas(16) float av[4][4], bv[4][4];
#pragma unroll
      for (int r = 0; r < 4; ++r) *(float4*)av[r] = *(const float4*)&As[tr + 16 * r][k0];
#pragma unroll
      for (int c = 0; c < 4; ++c) *(float4*)bv[c] = *(const float4*)&Bs[tc + 16 * c][k0];
#pragma unroll
      for (int kk = 0; kk < 4; ++kk)
#pragma unroll
        for (int r = 0; r < 4; ++r)
#pragma unroll
          for (int c = 0; c < 4; ++c)
            acc[r][c] = fmaf(av[r][kk], bv[c][kk], acc[r][c]);
    }
#pragma unroll
    for (int r = 0; r < 4; ++r)
#pragma unroll
      for (int c = 0; c < 4; ++c) {
        int row = tr + 16 * r, col = tc + 16 * c;
        float d2 = sqa[row] + sqjs[col] - 2.f * acc[r][c];
        float d = sqrtf(fmaxf(d2, EPSC));
        if (d < rsl[r]) {
          mxe[r] = fmaxf(mxe[r], ejs[col]);
          sd[r] += d;
          cnt[r] += 1;
        }
      }
  }
  __syncthreads();
#pragma unroll
  for (int r = 0; r < 4; ++r) mrgD[tr + 16 * r][tc] = mxe[r];
  __syncthreads();
  float depthv = 0.f, sdsum = 0.f;
  if (tid < 64) {
    float m = -FLT_MAX;
    for (int t = 0; t < 16; ++t) m = fmaxf(m, mrgD[tid][t]);
    depthv = m - eb[i0 + tid];
  }
  __syncthreads();
#pragma unroll
  for (int r = 0; r < 4; ++r) mrgD[tr + 16 * r][tc] = sd[r];
  __syncthreads();
  if (tid < 64) {
    float s = 0.f;
    for (int t = 0; t < 16; ++t) s += mrgD[tid][t];
    sdsum = s;
  }
  __syncthreads();
#pragma unroll
  for (int r = 0; r < 4; ++r) mrgD[tr + 16 * r][tc] = (float)cnt[r];
  __syncthreads();
  if (tid < 64) {
    float c = 0.f;
    for (int t = 0; t < 16; ++t) c += mrgD[tid][t];
    depth_out[(size_t)b * NPTS + i0 + tid] = depthv;
    width_out[(size_t)b * NPTS + i0 + tid] = sdsum / c;
  }
}

// ---------------------------------------------------------------------------
// Kernel 3: rank by nd (stable), scatter e into sorted order
// ---------------------------------------------------------------------------
__global__ __launch_bounds__(256) void rank_kernel(
    const float* __restrict__ nd_ws, const float* __restrict__ e_in,
    float* __restrict__ se_ws) {
  __shared__ __align__(16) float ndl[4096];
  const int tid = threadIdx.x;
  const int b = blockIdx.y;
  const int i0 = blockIdx.x * 256;
  const float* ndb = nd_ws + (size_t)b * NPTS;
  for (int q = tid; q < 1024; q += 256)
    *(float4*)&ndl[q * 4] = *(const float4*)(ndb + q * 4);
  __syncthreads();
  const int i = i0 + tid;
  const float ndi = ndl[i];
  int rank = 0;
  for (int j = 0; j < 4096; j += 4) {
    float4 v = *(const float4*)&ndl[j];
    rank += (v.x < ndi) || (v.x == ndi && (j + 0) < i);
    rank += (v.y < ndi) || (v.y == ndi && (j + 1) < i);
    rank += (v.z < ndi) || (v.z == ndi && (j + 2) < i);
    rank += (v.w < ndi) || (v.w == ndi && (j + 3) < i);
  }
  se_ws[(size_t)b * NPTS + rank] = e_in[(size_t)b * NPTS + i];
}

// ---------------------------------------------------------------------------
// Kernel 4: per-batch scalar metrics
// ---------------------------------------------------------------------------
__device__ __forceinline__ float block_sum(float v, float* red, int tid) {
  red[tid] = v;
  __syncthreads();
  for (int s = 512; s > 0; s >>= 1) {
    if (tid < s) red[tid] += red[tid + s];
    __syncthreads();
  }
  float r = red[0];
  __syncthreads();
  return r;
}
__device__ __forceinline__ float block_max(float v, float* red, int tid) {
  red[tid] = v;
  __syncthreads();
  for (int s = 512; s > 0; s >>= 1) {
    if (tid < s) red[tid] = fmaxf(red[tid], red[tid + s]);
    __syncthreads();
  }
  float r = red[0];
  __syncthreads();
  return r;
}

__global__ __launch_bounds__(1024) void metrics_kernel(
    const float* __restrict__ e_in, const float* __restrict__ nd_ws,
    const float* __restrict__ se_ws, float* __restrict__ metrics_out) {
  __shared__ __align__(16) float el[4096], ndl[4096], sel[4096];
  __shared__ float red[1024];
  __shared__ int redi[1024];
  const int tid = threadIdx.x;
  const int b = blockIdx.x;
  const float* eb = e_in + (size_t)b * NPTS;
  const float* ndb = nd_ws + (size_t)b * NPTS;
  const float* seb = se_ws + (size_t)b * NPTS;
  *(float4*)&el[tid * 4] = *(const float4*)(eb + tid * 4);
  *(float4*)&ndl[tid * 4] = *(const float4*)(ndb + tid * 4);
  *(float4*)&sel[tid * 4] = *(const float4*)(seb + tid * 4);
  __syncthreads();

  float pe = 0.f, pnd = 0.f;
  for (int p = tid; p < 4096; p += 1024) { pe += el[p]; pnd += ndl[p]; }
  float me = block_sum(pe, red, tid) / 4096.f;
  float mnd = block_sum(pnd, red, tid) / 4096.f;

  float sxx = 0.f, syy = 0.f, sxy = 0.f, mx = -FLT_MAX;
  float bestv = FLT_MAX;
  int besti = 0x7fffffff;
  for (int p = tid; p < 4096; p += 1024) {
    float de = el[p] - me, dn = ndl[p] - mnd;
    syy += de * de;
    sxx += dn * dn;
    sxy += de * dn;
    mx = fmaxf(mx, el[p]);
    if (ndl[p] < bestv || (ndl[p] == bestv && p < besti)) { bestv = ndl[p]; besti = p; }
  }
  float fr = 0.f;
  for (int p = tid; p < 4095; p += 1024) fr += (sel[p + 1] > sel[p]) ? 1.f : 0.f;

  sxx = block_sum(sxx, red, tid);
  syy = block_sum(syy, red, tid);
  sxy = block_sum(sxy, red, tid);
  mx = block_max(mx, red, tid);
  fr = block_sum(fr, red, tid);

  red[tid] = bestv;
  redi[tid] = besti;
  __syncthreads();
  for (int s = 512; s > 0; s >>= 1) {
    if (tid < s) {
      float ov = red[tid + s];
      int oi = redi[tid + s];
      if (ov < red[tid] || (ov == red[tid] && oi < redi[tid])) { red[tid] = ov; redi[tid] = oi; }
    }
    __syncthreads();
  }
  if (tid == 0) {
    float ne = el[redi[0]];
    metrics_out[b * 5 + 0] = mx - ne;
    metrics_out[b * 5 + 1] = sqrtf(syy / 4095.f);
    metrics_out[b * 5 + 2] = sxy / sqrtf(sxx * syy);
    metrics_out[b * 5 + 3] = fr / 4095.f;
    metrics_out[b * 5 + 4] = ne;
  }
}

// ---------------------------------------------------------------------------
extern "C" void kernel_launch(void* const* d_in, const int* in_sizes, int n_in,
                              void* d_out, int out_size, void* d_ws, size_t ws_size,
                              hipStream_t stream) {
  const float* conf = (const float*)d_in[0];
  const float* native = (const float*)d_in[1];
  const float* We1 = (const float*)d_in[2];
  const float* be1 = (const float*)d_in[3];
  const float* We2 = (const float*)d_in[4];
  const float* be2 = (const float*)d_in[5];
  const float* We3 = (const float*)d_in[6];
  const float* be3 = (const float*)d_in[7];
  const float* Ws1 = (const float*)d_in[8];
  const float* bs1 = (const float*)d_in[9];
  const float* Ws2 = (const float*)d_in[10];
  const float* bs2 = (const float*)d_in[11];

  float* out = (float*)d_out;
  float* e_out = out;                 // [0, 16384)
  float* basin_out = out + BN;        // [16384, 32768)
  float* depth_out = out + 2 * BN;    // [32768, 49152)
  float* width_out = out + 3 * BN;    // [49152, 65536)
  float* logits_out = out + 4 * BN;   // [65536, 163840)
  float* metrics_out = out + 10 * BN; // [163840, 163860)

  float* wsf = (float*)d_ws;
  float* sq_ws = wsf;            // BN floats
  float* nd_ws = wsf + BN;       // BN floats
  float* se_ws = wsf + 2 * BN;   // BN floats

  mlp_kernel<<<dim3(512), dim3(256), 0, stream>>>(
      conf, native, We1, be1, We2, be2, We3, be3, Ws1, bs1, Ws2, bs2,
      e_out, logits_out, sq_ws, nd_ws);
  dist_kernel<<<dim3(64, 4), dim3(256), 0, stream>>>(
      conf, sq_ws, e_out, basin_out, depth_out, width_out);
  rank_kernel<<<dim3(16, 4), dim3(256), 0, stream>>>(nd_ws, e_out, se_ws);
  metrics_kernel<<<dim3(4), dim3(1024), 0, stream>>>(e_out, nd_ws, se_ws, metrics_out);
}